// Round 1
// baseline (402.756 us; speedup 1.0000x reference)
//
#include <hip/hip_runtime.h>
#include <cstddef>
#include <cstdint>

typedef unsigned short u16;
typedef short short8 __attribute__((ext_vector_type(8)));
typedef float f32x4 __attribute__((ext_vector_type(4)));

#define M_DIM 4096
#define N_DIM 4096
#define K_DIM 512
#define NBATCH 8
#define TOT_ELEMS ((size_t)NBATCH * 4096 * 512)   // per-input element count

// ---------------- amax reduction (abs-max over whole tensor) ----------------
__global__ void amax_kernel(const float* __restrict__ x, unsigned* __restrict__ out) {
    const float4* x4 = (const float4*)x;
    const size_t n4 = TOT_ELEMS / 4;
    float m = 0.0f;
    for (size_t i = (size_t)blockIdx.x * blockDim.x + threadIdx.x; i < n4;
         i += (size_t)gridDim.x * blockDim.x) {
        float4 v = x4[i];
        m = fmaxf(m, fmaxf(fmaxf(fabsf(v.x), fabsf(v.y)), fmaxf(fabsf(v.z), fabsf(v.w))));
    }
    #pragma unroll
    for (int off = 32; off > 0; off >>= 1)
        m = fmaxf(m, __shfl_down(m, off, 64));
    if ((threadIdx.x & 63) == 0)
        atomicMax(out, __float_as_uint(m));   // bitwise max == float max for x >= 0
}

__device__ __forceinline__ float fq_scale(unsigned bits) {
    // scale = max(amax/448, 1e-12), correctly-rounded division like the reference
    return fmaxf(__uint_as_float(bits) / 448.0f, 1e-12f);
}

// quantize one float through fp8 e4m3 (HW RTNE + saturate), return bf16 bits (exact)
__device__ __forceinline__ u16 fq_to_bf16(float x, float scale) {
    float q = x / scale;                                   // IEEE fp32 divide, matches ref
    unsigned p = __builtin_amdgcn_cvt_pk_fp8_f32(q, q, 0u, false);
    float f = __builtin_amdgcn_cvt_f32_fp8(p, 0);
    return (u16)(__float_as_uint(f) >> 16);                // fp8 values are exact in bf16
}

// ---------------- quantize A: [B,M,K] fp32 -> bf16(q) same layout ----------------
__global__ void quant_a_kernel(const float* __restrict__ x, u16* __restrict__ q,
                               const unsigned* __restrict__ amaxbits) {
    const float scale = fq_scale(amaxbits[0]);
    const float4* x4 = (const float4*)x;
    ushort4* q4 = (ushort4*)q;
    const size_t n4 = TOT_ELEMS / 4;
    for (size_t i = (size_t)blockIdx.x * blockDim.x + threadIdx.x; i < n4;
         i += (size_t)gridDim.x * blockDim.x) {
        float4 v = x4[i];
        float a0 = v.x / scale, a1 = v.y / scale, a2 = v.z / scale, a3 = v.w / scale;
        unsigned p01 = __builtin_amdgcn_cvt_pk_fp8_f32(a0, a1, 0u, false);
        unsigned p23 = __builtin_amdgcn_cvt_pk_fp8_f32(a2, a3, 0u, false);
        ushort4 o;
        o.x = (u16)(__float_as_uint(__builtin_amdgcn_cvt_f32_fp8(p01, 0)) >> 16);
        o.y = (u16)(__float_as_uint(__builtin_amdgcn_cvt_f32_fp8(p01, 1)) >> 16);
        o.z = (u16)(__float_as_uint(__builtin_amdgcn_cvt_f32_fp8(p23, 0)) >> 16);
        o.w = (u16)(__float_as_uint(__builtin_amdgcn_cvt_f32_fp8(p23, 1)) >> 16);
        q4[i] = o;
    }
}

// ------- quantize + transpose B: [B,K,N] fp32 -> BT [B,N,K] bf16(q) -------
__global__ void quant_bt_kernel(const float* __restrict__ x, u16* __restrict__ bt,
                                const unsigned* __restrict__ amaxbits) {
    __shared__ u16 tile[64][66];   // 66 stride -> conflict-free transposed u16 access
    const float scale = fq_scale(amaxbits[1]);
    const int n0 = blockIdx.x * 64, k0 = blockIdx.y * 64, b = blockIdx.z;
    const int tx = threadIdx.x, ty = threadIdx.y;          // block (64,4)
    const float* xb = x + (size_t)b * K_DIM * N_DIM;
    #pragma unroll
    for (int r = ty; r < 64; r += 4)
        tile[tx][r] = fq_to_bf16(xb[(size_t)(k0 + r) * N_DIM + n0 + tx], scale);
    __syncthreads();
    u16* btb = bt + (size_t)b * N_DIM * K_DIM;
    #pragma unroll
    for (int r = ty; r < 64; r += 4)
        btb[(size_t)(n0 + r) * K_DIM + k0 + tx] = tile[r][tx];
}

// ---------------- GEMM: C[b] = (s1*s2) * Aq[b] @ BqT[b]^T ----------------
// m97 structure: 128x128 tile, BK=32, 4 waves (2x2), global_load_lds width 16.
#define GLD_LDS16(g, l)                                                         \
    __builtin_amdgcn_global_load_lds(                                           \
        (const __attribute__((address_space(1))) void*)(g),                     \
        (__attribute__((address_space(3))) void*)(l), 16, 0, 0)

__global__ __launch_bounds__(256) void gemm_kernel(
    const u16* __restrict__ Aq, const u16* __restrict__ Bq,
    float* __restrict__ C, const unsigned* __restrict__ amaxbits) {
    __shared__ u16 ldsA[128 * 32];
    __shared__ u16 ldsB[128 * 32];
    const int t = threadIdx.x;
    const int w = t >> 6, l = t & 63;
    const int b = blockIdx.z;
    const size_t boff = (size_t)b * (size_t)M_DIM * K_DIM;
    const u16* A = Aq + boff + (size_t)blockIdx.y * 128 * K_DIM;
    const u16* B = Bq + boff + (size_t)blockIdx.x * 128 * K_DIM;

    const int wr = w >> 1, wc = w & 1;       // 2x2 waves, each owns 64x64
    const int lrow = l & 15, kgrp = l >> 4;  // MFMA fragment addressing

    // staging: 512 16B-chunks per tile; chunk c -> row c>>2, k-quad c&3
    const int c0 = t, c1 = t + 256;
    const int r0s = c0 >> 2, q0s = c0 & 3;
    const int r1s = c1 >> 2, q1s = c1 & 3;

    f32x4 acc[4][4] = {};

    for (int kt = 0; kt < 16; ++kt) {
        const int ko = kt * 32;
        // ---- stage A,B tiles (LDS dest base must be wave-uniform) ----
        GLD_LDS16(A + (size_t)r0s * K_DIM + ko + q0s * 8, &ldsA[(w * 64) * 8]);
        GLD_LDS16(A + (size_t)r1s * K_DIM + ko + q1s * 8, &ldsA[(256 + w * 64) * 8]);
        GLD_LDS16(B + (size_t)r0s * K_DIM + ko + q0s * 8, &ldsB[(w * 64) * 8]);
        GLD_LDS16(B + (size_t)r1s * K_DIM + ko + q1s * 8, &ldsB[(256 + w * 64) * 8]);
        asm volatile("s_waitcnt vmcnt(0)" ::: "memory");
        __syncthreads();

        short8 af[4], bfr[4];
        #pragma unroll
        for (int m = 0; m < 4; ++m)
            af[m] = *(const short8*)&ldsA[(wr * 64 + m * 16 + lrow) * 32 + kgrp * 8];
        #pragma unroll
        for (int n = 0; n < 4; ++n)
            bfr[n] = *(const short8*)&ldsB[(wc * 64 + n * 16 + lrow) * 32 + kgrp * 8];
        #pragma unroll
        for (int m = 0; m < 4; ++m)
            #pragma unroll
            for (int n = 0; n < 4; ++n)
                acc[m][n] = __builtin_amdgcn_mfma_f32_16x16x32_bf16(af[m], bfr[n],
                                                                    acc[m][n], 0, 0, 0);
        __syncthreads();
    }

    // ---- epilogue: dequant scale + store ----
    const float s12 = fq_scale(amaxbits[0]) * fq_scale(amaxbits[1]);
    float* Cb = C + (size_t)b * ((size_t)M_DIM * N_DIM);
    const int rbase = blockIdx.y * 128 + wr * 64 + kgrp * 4;
    const int cbase = blockIdx.x * 128 + wc * 64 + lrow;
    #pragma unroll
    for (int m = 0; m < 4; ++m)
        #pragma unroll
        for (int n = 0; n < 4; ++n)
            #pragma unroll
            for (int j = 0; j < 4; ++j)
                Cb[(size_t)(rbase + m * 16 + j) * N_DIM + (cbase + n * 16)] =
                    acc[m][n][j] * s12;
}

// ---------------- launch ----------------
extern "C" void kernel_launch(void* const* d_in, const int* in_sizes, int n_in,
                              void* d_out, int out_size, void* d_ws, size_t ws_size,
                              hipStream_t stream) {
    const float* in1 = (const float*)d_in[0];
    const float* in2 = (const float*)d_in[1];
    float* out = (float*)d_out;

    unsigned* amax = (unsigned*)d_ws;
    u16* Aq = (u16*)((char*)d_ws + 256);
    u16* Bq = (u16*)((char*)d_ws + 256 + TOT_ELEMS * sizeof(u16));

    hipMemsetAsync(d_ws, 0, 64, stream);  // zero amax slots (ws is poisoned)

    hipLaunchKernelGGL(amax_kernel, dim3(1024), dim3(256), 0, stream, in1, amax + 0);
    hipLaunchKernelGGL(amax_kernel, dim3(1024), dim3(256), 0, stream, in2, amax + 1);
    hipLaunchKernelGGL(quant_a_kernel, dim3(2048), dim3(256), 0, stream, in1, Aq, amax);
    hipLaunchKernelGGL(quant_bt_kernel, dim3(N_DIM / 64, K_DIM / 64, NBATCH),
                       dim3(64, 4), 0, stream, in2, Bq, amax);
    hipLaunchKernelGGL(gemm_kernel, dim3(N_DIM / 128, M_DIM / 128, NBATCH),
                       dim3(256), 0, stream, Aq, Bq, out, amax);
}

// Round 2
// 315.880 us; speedup vs baseline: 1.2750x; 1.2750x over previous
//
#include <hip/hip_runtime.h>
#include <cstddef>
#include <cstdint>

typedef unsigned short u16;
typedef unsigned char u8;
typedef int i32x4 __attribute__((ext_vector_type(4)));
typedef int i32x8 __attribute__((ext_vector_type(8)));
typedef float f32x16 __attribute__((ext_vector_type(16)));

#define M_DIM 4096
#define N_DIM 4096
#define K_DIM 512
#define NBATCH 8
#define TOT_ELEMS ((size_t)NBATCH * 4096 * 512)   // per-input element count

// ---------------- amax reduction (abs-max over whole tensor) ----------------
__global__ void amax_kernel(const float* __restrict__ x, unsigned* __restrict__ out) {
    const float4* x4 = (const float4*)x;
    const size_t n4 = TOT_ELEMS / 4;
    float m = 0.0f;
    for (size_t i = (size_t)blockIdx.x * blockDim.x + threadIdx.x; i < n4;
         i += (size_t)gridDim.x * blockDim.x) {
        float4 v = x4[i];
        m = fmaxf(m, fmaxf(fmaxf(fabsf(v.x), fabsf(v.y)), fmaxf(fabsf(v.z), fabsf(v.w))));
    }
    #pragma unroll
    for (int off = 32; off > 0; off >>= 1)
        m = fmaxf(m, __shfl_down(m, off, 64));
    if ((threadIdx.x & 63) == 0)
        atomicMax(out, __float_as_uint(m));   // bitwise max == float max for x >= 0
}

__device__ __forceinline__ float fq_scale(unsigned bits) {
    return fmaxf(__uint_as_float(bits) / 448.0f, 1e-12f);   // max(amax/448, 1e-12)
}

// ---------------- quantize A: [B,M,K] fp32 -> fp8 bytes, same layout ----------------
__global__ void quant_a_kernel(const float* __restrict__ x, unsigned* __restrict__ q,
                               const unsigned* __restrict__ amaxbits) {
    const float scale = fq_scale(amaxbits[0]);
    const float4* x4 = (const float4*)x;
    const size_t n4 = TOT_ELEMS / 4;
    for (size_t i = (size_t)blockIdx.x * blockDim.x + threadIdx.x; i < n4;
         i += (size_t)gridDim.x * blockDim.x) {
        float4 v = x4[i];
        unsigned p = __builtin_amdgcn_cvt_pk_fp8_f32(v.x / scale, v.y / scale, 0u, false);
        p = __builtin_amdgcn_cvt_pk_fp8_f32(v.z / scale, v.w / scale, p, true);
        q[i] = p;   // 4 fp8 bytes
    }
}

// ------- quantize + transpose B: [B,K,N] fp32 -> BT [B,N,K] fp8 bytes -------
__global__ void quant_bt_kernel(const float* __restrict__ x, u8* __restrict__ bt,
                                const unsigned* __restrict__ amaxbits) {
    __shared__ __align__(16) u8 tile[64][68];   // [n][k], pad keeps rows 4B-aligned, spreads banks
    const float scale = fq_scale(amaxbits[1]);
    const int n0 = blockIdx.x * 64, k0 = blockIdx.y * 64, b = blockIdx.z;
    const int t = threadIdx.x;                  // 256 threads
    const int cg = (t & 15) * 4;
    const float* xb = x + (size_t)b * K_DIM * N_DIM;
    #pragma unroll
    for (int r = t >> 4; r < 64; r += 16) {     // r = k index
        float4 v = *(const float4*)&xb[(size_t)(k0 + r) * N_DIM + n0 + cg];
        unsigned p01 = __builtin_amdgcn_cvt_pk_fp8_f32(v.x / scale, v.y / scale, 0u, false);
        unsigned p23 = __builtin_amdgcn_cvt_pk_fp8_f32(v.z / scale, v.w / scale, 0u, false);
        tile[cg + 0][r] = (u8)(p01 & 0xff);
        tile[cg + 1][r] = (u8)((p01 >> 8) & 0xff);
        tile[cg + 2][r] = (u8)(p23 & 0xff);
        tile[cg + 3][r] = (u8)((p23 >> 8) & 0xff);
    }
    __syncthreads();
    u8* btb = bt + (size_t)b * N_DIM * K_DIM;
    #pragma unroll
    for (int n = t >> 4; n < 64; n += 16) {     // n = output row
        uchar4 o;
        o.x = tile[n][cg + 0]; o.y = tile[n][cg + 1];
        o.z = tile[n][cg + 2]; o.w = tile[n][cg + 3];
        *(uchar4*)&btb[(size_t)(n0 + n) * K_DIM + k0 + cg] = o;
    }
}

// ---------------- GEMM: C[b] = (s1*s2) * Aq[b] @ BqT[b]^T  (MX-fp8, unit scales) ----
#define GLD_LDS16(g, l)                                                         \
    __builtin_amdgcn_global_load_lds(                                           \
        (const __attribute__((address_space(1))) void*)(g),                     \
        (__attribute__((address_space(3))) void*)(l), 16, 0, 0)

// 128x128 tile, BK=128 (bytes), 4 waves (2x2, each 64x64 out), mfma_scale 32x32x64.
// LDS rows are 128B -> naive column reads = 32-way bank conflict; granule-XOR swizzle
// (g ^= row&7) applied on the GLOBAL source (rule #21: gload_lds writes linearly) and
// on the ds_read address; fragments assembled from two independent b128 reads.
__global__ __launch_bounds__(256) void gemm_kernel(
    const u8* __restrict__ Aq, const u8* __restrict__ Bq,
    float* __restrict__ C, const unsigned* __restrict__ amaxbits) {
    __shared__ __align__(16) u8 ldsA[128 * 128];
    __shared__ __align__(16) u8 ldsB[128 * 128];
    const int t = threadIdx.x;
    const int w = t >> 6, l = t & 63;
    const int b = blockIdx.z;
    const u8* A = Aq + (size_t)b * M_DIM * K_DIM + (size_t)blockIdx.y * 128 * K_DIM;
    const u8* B = Bq + (size_t)b * N_DIM * K_DIM + (size_t)blockIdx.x * 128 * K_DIM;

    const int wr = w >> 1, wc = w & 1;   // 2x2 waves
    const int lr = l & 31, lh = l >> 5;  // MFMA 32x32 lane split

    f32x16 acc[2][2] = {};

    for (int kt = 0; kt < 4; ++kt) {
        const int ko = kt * 128;
        // ---- stage: 1024 16B-chunks per tile; chunk c -> row c>>3, granule c&7.
        // LDS linear (wave-uniform base + lane*16); source granule pre-swizzled.
        #pragma unroll
        for (int i = 0; i < 4; ++i) {
            const int c = t + i * 256;
            const int row = c >> 3, g = c & 7;
            const int sg = g ^ (row & 7);
            GLD_LDS16(A + (size_t)row * K_DIM + ko + sg * 16, &ldsA[(w * 64 + i * 256) * 16]);
        }
        #pragma unroll
        for (int i = 0; i < 4; ++i) {
            const int c = t + i * 256;
            const int row = c >> 3, g = c & 7;
            const int sg = g ^ (row & 7);
            GLD_LDS16(B + (size_t)row * K_DIM + ko + sg * 16, &ldsB[(w * 64 + i * 256) * 16]);
        }
        asm volatile("s_waitcnt vmcnt(0)" ::: "memory");
        __syncthreads();

        // ---- 2 k-sub MFMAs (K=64 each) per 32x32 output block
        #pragma unroll
        for (int ksub = 0; ksub < 2; ++ksub) {
            const int g0 = ksub * 4 + lh * 2;   // first 16B granule of this lane's 32B
            i32x8 af[2], bfr[2];
            #pragma unroll
            for (int m = 0; m < 2; ++m) {
                const int ar = wr * 64 + m * 32 + lr;
                i32x4 lo = *(const i32x4*)&ldsA[ar * 128 + ((g0 + 0) ^ (ar & 7)) * 16];
                i32x4 hi = *(const i32x4*)&ldsA[ar * 128 + ((g0 + 1) ^ (ar & 7)) * 16];
                af[m] = __builtin_shufflevector(lo, hi, 0, 1, 2, 3, 4, 5, 6, 7);
            }
            #pragma unroll
            for (int n = 0; n < 2; ++n) {
                const int br = wc * 64 + n * 32 + lr;
                i32x4 lo = *(const i32x4*)&ldsB[br * 128 + ((g0 + 0) ^ (br & 7)) * 16];
                i32x4 hi = *(const i32x4*)&ldsB[br * 128 + ((g0 + 1) ^ (br & 7)) * 16];
                bfr[n] = __builtin_shufflevector(lo, hi, 0, 1, 2, 3, 4, 5, 6, 7);
            }
            #pragma unroll
            for (int m = 0; m < 2; ++m)
                #pragma unroll
                for (int n = 0; n < 2; ++n)
                    acc[m][n] = __builtin_amdgcn_mfma_scale_f32_32x32x64_f8f6f4(
                        af[m], bfr[n], acc[m][n], 0, 0, 0, 127, 0, 127);  // e8m0 127 = 2^0
        }
        __syncthreads();
    }

    // ---- epilogue: dequant scale + store (32x32 C/D: col=lane&31, row=(r&3)+8*(r>>2)+4*lh)
    const float s12 = fq_scale(amaxbits[0]) * fq_scale(amaxbits[1]);
    float* Cb = C + (size_t)b * ((size_t)M_DIM * N_DIM);
    #pragma unroll
    for (int m = 0; m < 2; ++m) {
        const int rbase = blockIdx.y * 128 + wr * 64 + m * 32 + 4 * lh;
        #pragma unroll
        for (int n = 0; n < 2; ++n) {
            const int col = blockIdx.x * 128 + wc * 64 + n * 32 + lr;
            #pragma unroll
            for (int r = 0; r < 16; ++r) {
                const int row = rbase + (r & 3) + 8 * (r >> 2);
                Cb[(size_t)row * N_DIM + col] = acc[m][n][r] * s12;
            }
        }
    }
}

// ---------------- launch ----------------
extern "C" void kernel_launch(void* const* d_in, const int* in_sizes, int n_in,
                              void* d_out, int out_size, void* d_ws, size_t ws_size,
                              hipStream_t stream) {
    const float* in1 = (const float*)d_in[0];
    const float* in2 = (const float*)d_in[1];
    float* out = (float*)d_out;

    unsigned* amax = (unsigned*)d_ws;
    u8* Aq = (u8*)((char*)d_ws + 256);
    u8* Bq = (u8*)((char*)d_ws + 256 + TOT_ELEMS);

    hipMemsetAsync(d_ws, 0, 64, stream);  // zero amax slots (ws is poisoned)

    hipLaunchKernelGGL(amax_kernel, dim3(1024), dim3(256), 0, stream, in1, amax + 0);
    hipLaunchKernelGGL(amax_kernel, dim3(1024), dim3(256), 0, stream, in2, amax + 1);
    hipLaunchKernelGGL(quant_a_kernel, dim3(2048), dim3(256), 0, stream, in1,
                       (unsigned*)Aq, amax);
    hipLaunchKernelGGL(quant_bt_kernel, dim3(N_DIM / 64, K_DIM / 64, NBATCH),
                       dim3(256), 0, stream, in2, Bq, amax);
    hipLaunchKernelGGL(gemm_kernel, dim3(N_DIM / 128, M_DIM / 128, NBATCH),
                       dim3(256), 0, stream, Aq, Bq, out, amax);
}